// Round 1
// baseline (5760.788 us; speedup 1.0000x reference)
//
#include <hip/hip_runtime.h>

// Problem shape (fixed by reference setup_inputs)
constexpr int MM = 4096;   // tokens
constexpr int NN = 8192;   // outfeatures
constexpr int KK = 8192;   // infeatures
constexpr int BM = 256, BN = 256, BK = 64;
constexpr int THREADS = 512;   // 8 waves: 4 along M x 2 along N; wave tile 64x128
constexpr int NKB = KK / BK;   // 128
constexpr int NT = NN / BN;    // 32
constexpr int NGROUPS = 64;

typedef _Float16 f16;
typedef __attribute__((ext_vector_type(2))) _Float16 f16x2;
typedef __attribute__((ext_vector_type(8))) _Float16 f16x8;
typedef __attribute__((ext_vector_type(4))) float floatx4;
typedef __attribute__((ext_vector_type(4))) int intx4;

__device__ __forceinline__ void async_copy16(const void* g, void* l) {
    __builtin_amdgcn_global_load_lds(
        (const __attribute__((address_space(1))) void*)g,
        (__attribute__((address_space(3))) void*)l, 16, 0, 0);
}

// ---------------------------------------------------------------------------
// Single fused kernel.
//  - A: x (f32) DMA'd to LDS via global_load_lds, double-buffered 2x64KB.
//       XOR-16 chunk swizzle applied on the GLOBAL source (LDS dest linear),
//       f32->f16 conversion at fragment read via v_cvt_pkrtz (pairs k,k+4).
//  - B: one qweight dword per lane per fragment, loaded one K-block ahead,
//       dequantized in registers with packed-f16 magic:
//         t = (u>>s & 0x000F000F) | 0x64006400   -> (1024+n_j, 1024+n_{j+4})
//         w = pk_mul(pk_add(t, -(1024+z)), s)    -> exact (n - z) * s
//       K-order inside each octet is (0,4,1,5,2,6,3,7) on BOTH operands.
//  - One __syncthreads per K-block (A buffer flip only).
// ---------------------------------------------------------------------------
__global__ __launch_bounds__(THREADS, 2)
void qgemm(const float* __restrict__ x,
           const unsigned* __restrict__ qweight,
           const unsigned* __restrict__ qzeros,
           const float* __restrict__ scales,
           const float* __restrict__ bias,
           float* __restrict__ out)
{
    __shared__ alignas(16) float As[2][BM * BK];   // 2 x 64 KB

    const int t = threadIdx.x;
    const int ntile = blockIdx.x & (NT - 1);   // n fastest: share x m-tile
    const int mtile = blockIdx.x / NT;
    const int n0 = ntile * BN;

    const int wave = t >> 6;
    const int lane = t & 63;
    const int wm = (wave >> 1) * 64;    // 4 waves along M
    const int wn = (wave & 1) * 128;    // 2 waves along N
    const int ml = lane & 15;
    const int quad = lane >> 4;

    // ---- B per-lane indexing ----
    const int colb = n0 + wn + ml;                    // + jn*16
    const unsigned qcolq = (unsigned)colb + (unsigned)quad * NN;  // fold quad*NN
    const int zsh = 4 * (ml & 7);                     // col&7 == ml&7 (jn*16 % 8 == 0)

    floatx4 acc[4][8];
#pragma unroll
    for (int i = 0; i < 4; ++i)
#pragma unroll
        for (int j = 0; j < 8; ++j)
            acc[i][j] = (floatx4){0.f, 0.f, 0.f, 0.f};

    // ---- state registers ----
    unsigned bq[16];            // raw qweight dwords for current kb [ks*8+jn]
    unsigned s_pk[8], nzp[8];   // current group: packed f16 scale / -(1024+z)
    float    s_raw[8];          // next group staging
    unsigned z_raw[8];

    // -------------------------------------------------------------------
    // A staging: whole 256x64 f32 tile, cooperatively. Wave w stages rows
    // [w*32, w*32+32). DMA instr i covers 4 rows (lane>>4) x 16 chunks
    // (lane&15). LDS is linear; the 16B-chunk XOR swizzle is applied to the
    // global source: LDS slot (r, cc) holds global chunk cc ^ (r & 15).
    // -------------------------------------------------------------------
    auto stage_a = [&](int kb, int buf) {
#pragma unroll
        for (int i = 0; i < 8; ++i) {
            const int r = wave * 32 + i * 4 + (lane >> 4);   // row in tile
            const int gc = (lane & 15) ^ (r & 15);           // global chunk
            const float* g = x + (unsigned)((mtile * BM + r) * KK + kb * BK + gc * 4);
            char* l = (char*)&As[buf][(wave * 32 + i * 4) * BK];  // wave-uniform
            async_copy16(g, l);
        }
    };

    // fragment read: f32 LDS -> f16x8 in (k0,k4,k1,k5,k2,k6,k3,k7) order
    auto load_af = [&](int buf, int ks, f16x8 (&af)[4]) {
#pragma unroll
        for (int im = 0; im < 4; ++im) {
            const int r = wm + im * 16 + ml;
            const int cbase = (ks * 4 + quad) * 2;
            const int c0 = (cbase + 0) ^ (r & 15);
            const int c1 = (cbase + 1) ^ (r & 15);
            const float4 a0 = *(const float4*)&As[buf][r * BK + c0 * 4];  // k0..k3
            const float4 a1 = *(const float4*)&As[buf][r * BK + c1 * 4];  // k4..k7
            const auto p0 = __builtin_amdgcn_cvt_pkrtz(a0.x, a1.x);
            const auto p1 = __builtin_amdgcn_cvt_pkrtz(a0.y, a1.y);
            const auto p2 = __builtin_amdgcn_cvt_pkrtz(a0.z, a1.z);
            const auto p3 = __builtin_amdgcn_cvt_pkrtz(a0.w, a1.w);
            const intx4 ai = { __builtin_bit_cast(int, p0), __builtin_bit_cast(int, p1),
                               __builtin_bit_cast(int, p2), __builtin_bit_cast(int, p3) };
            af[im] = __builtin_bit_cast(f16x8, ai);
        }
    };

    // raw B loads for K-block kb (one dword per lane per fragment)
    auto load_bq = [&](int kb, int ks, int jh) {
        const unsigned rowoff = (unsigned)(kb * 8 + ks * 4) * NN;
#pragma unroll
        for (int j = 0; j < 4; ++j) {
            const int jn = jh * 4 + j;
            bq[ks * 8 + jn] = qweight[rowoff + qcolq + jn * 16];
        }
    };

    auto group_fetch = [&](int g) {
#pragma unroll
        for (int jn = 0; jn < 8; ++jn) {
            const int col = colb + jn * 16;
            s_raw[jn] = scales[(unsigned)(g * NN + col)];
            z_raw[jn] = qzeros[(unsigned)(g * (NN / 8) + (col >> 3))];
        }
    };
    auto group_convert = [&]() {
#pragma unroll
        for (int jn = 0; jn < 8; ++jn) {
            const unsigned short sh = __builtin_bit_cast(unsigned short, (f16)s_raw[jn]);
            s_pk[jn] = ((unsigned)sh << 16) | sh;
            const unsigned z = (z_raw[jn] >> zsh) & 15u;
            const unsigned nh = 0xE401u + z;          // f16 bits of -(1024 + z + 1)
            nzp[jn] = (nh << 16) | nh;
        }
    };

    // dequant 4 fragments + 16 MFMA
    auto phase = [&](int ks, int jh, const f16x8 (&af)[4]) {
        __builtin_amdgcn_s_setprio(1);
#pragma unroll
        for (int j = 0; j < 4; ++j) {
            const int jn = jh * 4 + j;
            const unsigned u = bq[ks * 8 + jn];
            const unsigned t0 = ( u         & 0x000F000Fu) | 0x64006400u;
            const unsigned t1 = ((u >> 4)   & 0x000F000Fu) | 0x64006400u;
            const unsigned t2 = ((u >> 8)   & 0x000F000Fu) | 0x64006400u;
            const unsigned t3 = ((u >> 12)  & 0x000F000Fu) | 0x64006400u;
            const f16x2 z2 = __builtin_bit_cast(f16x2, nzp[jn]);
            const f16x2 sp = __builtin_bit_cast(f16x2, s_pk[jn]);
            const f16x2 w0 = (__builtin_bit_cast(f16x2, t0) + z2) * sp;
            const f16x2 w1 = (__builtin_bit_cast(f16x2, t1) + z2) * sp;
            const f16x2 w2 = (__builtin_bit_cast(f16x2, t2) + z2) * sp;
            const f16x2 w3 = (__builtin_bit_cast(f16x2, t3) + z2) * sp;
            const intx4 bi = { __builtin_bit_cast(int, w0), __builtin_bit_cast(int, w1),
                               __builtin_bit_cast(int, w2), __builtin_bit_cast(int, w3) };
            const f16x8 bf = __builtin_bit_cast(f16x8, bi);
#pragma unroll
            for (int im = 0; im < 4; ++im)
                acc[im][jn] = __builtin_amdgcn_mfma_f32_16x16x32_f16(
                    af[im], bf, acc[im][jn], 0, 0, 0);
        }
        __builtin_amdgcn_s_setprio(0);
    };

    // One K-block: compute buf, stage buf^1 for kb+1.
    auto body = [&](int kb, int buf, bool stage) {
        f16x8 af0[4], af1[4];
        if (stage) stage_a(kb + 1, buf ^ 1);   // DMA earliest: longest window
        load_af(buf, 0, af0);
        phase(0, 0, af0);
        if (stage) load_bq(kb + 1, 0, 0);      // reload consumed regs (WAR)
        load_af(buf, 1, af1);                  // overlaps phase(0,1) MFMAs
        phase(0, 1, af0);
        if (stage) load_bq(kb + 1, 0, 1);
        if (stage && ((kb & 1) == 0)) {
            int g = (kb >> 1) + 1;
            if (g > NGROUPS - 1) g = NGROUPS - 1;   // clamp at last group
            group_fetch(g);
        }
        phase(1, 0, af1);
        if (stage) load_bq(kb + 1, 1, 0);
        phase(1, 1, af1);
        if (stage) load_bq(kb + 1, 1, 1);
        if (stage && ((kb & 1) == 1)) group_convert();
        if (stage) __syncthreads();            // publish As[buf^1]; flip
    };

    // ---- prologue ----
    group_fetch(0);
    stage_a(0, 0);
    load_bq(0, 0, 0); load_bq(0, 0, 1); load_bq(0, 1, 0); load_bq(0, 1, 1);
    group_convert();
    __syncthreads();

    // ---- main loop, unrolled x2 for static buffer indices ----
    for (int kb = 0; kb < NKB - 2; kb += 2) {
        body(kb, 0, true);
        body(kb + 1, 1, true);
    }
    body(NKB - 2, 0, true);
    body(NKB - 1, 1, false);

    // ---- epilogue: C/D layout col=lane&15, row=quad*4+reg; add bias ----
#pragma unroll
    for (int jn = 0; jn < 8; ++jn) {
        const int ngl = n0 + wn + jn * 16 + ml;
        const float bv = bias[ngl];
#pragma unroll
        for (int im = 0; im < 4; ++im) {
            const int mg = mtile * BM + wm + im * 16 + quad * 4;
#pragma unroll
            for (int r = 0; r < 4; ++r)
                out[(size_t)(mg + r) * NN + ngl] = acc[im][jn][r] + bv;
        }
    }
}

extern "C" void kernel_launch(void* const* d_in, const int* in_sizes, int n_in,
                              void* d_out, int out_size, void* d_ws, size_t ws_size,
                              hipStream_t stream) {
    const float*    x       = (const float*)d_in[0];
    const unsigned* qweight = (const unsigned*)d_in[1];
    const unsigned* qzeros  = (const unsigned*)d_in[2];
    const float*    scales  = (const float*)d_in[3];
    const float*    bias    = (const float*)d_in[4];
    float* out = (float*)d_out;

    const int grid = (MM / BM) * (NN / BN);   // 512 blocks
    qgemm<<<grid, THREADS, 0, stream>>>(x, qweight, qzeros, scales, bias, out);
}

// Round 2
// 1725.625 us; speedup vs baseline: 3.3384x; 3.3384x over previous
//
#include <hip/hip_runtime.h>
#include <hip/hip_bf16.h>

// Problem shape (fixed by reference setup_inputs)
constexpr int MM = 4096;   // tokens
constexpr int NN = 8192;   // outfeatures
constexpr int KK = 8192;   // infeatures
constexpr int BM = 256, BN = 256, BK = 64;
constexpr int THREADS = 512;   // 8 waves: 4 along M x 2 along N; wave tile 64x128
constexpr int NKB = KK / BK;   // 128
constexpr int NT = NN / BN;    // 32

typedef _Float16 f16;
typedef __attribute__((ext_vector_type(2))) _Float16 f16x2;
typedef __attribute__((ext_vector_type(8))) _Float16 f16x8;
typedef __attribute__((ext_vector_type(4))) float floatx4;
typedef __attribute__((ext_vector_type(4))) int intx4;
typedef __bf16 bf16;
typedef __attribute__((ext_vector_type(8))) __bf16 bf16x8;

__device__ __forceinline__ void async_copy16(const void* g, void* l) {
    __builtin_amdgcn_global_load_lds(
        (const __attribute__((address_space(1))) void*)g,
        (__attribute__((address_space(3))) void*)l, 16, 0, 0);
}

// ---------------------------------------------------------------------------
// Prep: x fp32 -> f16, tile-major [mtile][kb][m][chunk^swizzle], with the
// (k, k+4) pair order baked into each 8-elem chunk so the GEMM's B-side
// nibble dequant (pairs (n_j, n_{j+4}) per dword half) matches slot-for-slot.
// Tile image is byte-identical to its LDS image -> global_load_lds DMA.
// ---------------------------------------------------------------------------
__global__ __launch_bounds__(256)
void convert_x(const float* __restrict__ x, f16* __restrict__ xb) {
    const int tid = blockIdx.x * 256 + threadIdx.x;   // one 16B chunk (8 elems)
    const int c = tid & 7;
    const int m = (tid >> 3) & 255;
    const int kb = (tid >> 11) & 127;
    const int mtile = tid >> 18;
    const int row = mtile * 256 + m;
    const int col = kb * 64 + c * 8;
    const float4* src = (const float4*)(x + (size_t)row * KK + col);
    const float4 f0 = src[0];   // k0..k3
    const float4 f1 = src[1];   // k4..k7
    f16x8 v;                    // pair order (k0,k4,k1,k5,k2,k6,k3,k7)
    v[0] = (f16)f0.x; v[1] = (f16)f1.x;
    v[2] = (f16)f0.y; v[3] = (f16)f1.y;
    v[4] = (f16)f0.z; v[5] = (f16)f1.z;
    v[6] = (f16)f0.w; v[7] = (f16)f1.w;
    const int dst_chunk = (tid & ~7) | (c ^ (m & 7));
    *(f16x8*)(xb + (size_t)dst_chunk * 8) = v;
}

// ---------------------------------------------------------------------------
// Main GEMM.
//  - A: f16 tiles DMA'd via global_load_lds, double-buffered 2x32KB,
//       one barrier per K-block (round-0 proven structure).
//  - B: one qweight dword per lane per fragment, loaded one K-block ahead
//       (quarter-reload right after each phase consumes its quarter),
//       dequantized IN REGISTERS with packed-f16 magic:
//         t = (u>>s & 0x000F000F) | 0x64006400 -> (1024+n_j, 1024+n_{j+4})
//         w = (t + (-(1024+z))) * scale        -> exact (n - z) * s
//       No B LDS traffic at all.
//  - Group state (8 cols/lane): s_pk/nzp packed-f16 pairs; next-group fetch
//    staged mid-odd-body, converted AFTER the barrier (vmcnt already 0).
// ---------------------------------------------------------------------------
__global__ __launch_bounds__(THREADS, 2)
void qgemm(const f16* __restrict__ xb,
           const unsigned* __restrict__ qweight,
           const unsigned* __restrict__ qzeros,
           const float* __restrict__ scales,
           const float* __restrict__ bias,
           float* __restrict__ out)
{
    __shared__ alignas(16) f16 As[2][BM * BK];   // 2 x 32 KB

    const int t = threadIdx.x;
    const int ntile = blockIdx.x & (NT - 1);   // n fastest: share x m-tile
    const int mtile = blockIdx.x / NT;
    const int n0 = ntile * BN;

    const int wave = t >> 6;
    const int lane = t & 63;
    const int wm = (wave >> 1) * 64;    // 4 waves along M
    const int wn = (wave & 1) * 128;    // 2 waves along N
    const int ml = lane & 15;
    const int quad = lane >> 4;

    // ---- B per-lane indexing ----
    const int colb = n0 + wn + ml;                    // + jn*16
    const unsigned qcol = (unsigned)colb + (unsigned)quad * NN;   // fold quad row
    const int zsh = 4 * (ml & 7);                     // col&7 == ml&7

    floatx4 acc[4][8];
#pragma unroll
    for (int i = 0; i < 4; ++i)
#pragma unroll
        for (int j = 0; j < 8; ++j)
            acc[i][j] = (floatx4){0.f, 0.f, 0.f, 0.f};

    // ---- state registers ----
    unsigned bq[16];            // raw qweight dwords for current kb [ks*8+jn]
    unsigned s_pk[8], nzp[8];   // current group: packed f16 scale / -(1024+z+1)
    float    s_raw[8];          // next-group scale staging
    unsigned zp_stage = 0;      // next-group zeros, 8 nibbles packed

    const char* xb_base = (const char*)xb
        + (size_t)mtile * NKB * (BM * BK) * sizeof(f16);

    auto stage_a = [&](int kb, int buf) {
        const char* g = xb_base + (size_t)kb * (BM * BK * 2) + wave * 4096 + lane * 16;
        char* l = (char*)&As[buf][0] + wave * 4096;   // wave-uniform; HW adds lane*16
#pragma unroll
        for (int i = 0; i < 4; ++i)
            async_copy16(g + i * 1024, l + i * 1024);
    };

    auto load_af = [&](int buf, int ks, f16x8 (&af)[4]) {
#pragma unroll
        for (int im = 0; im < 4; ++im) {
            const int r = wm + im * 16 + ml;
            const int clog = ks * 4 + quad;
            af[im] = *(const f16x8*)&As[buf][r * BK + ((clog ^ (r & 7)) << 3)];
        }
    };

    auto load_bq = [&](int kb, int ks, int jh) {
        const unsigned rowoff = (unsigned)(kb * 8 + ks * 4) * NN;
#pragma unroll
        for (int j = 0; j < 4; ++j) {
            const int jn = jh * 4 + j;
            bq[ks * 8 + jn] = qweight[rowoff + qcol + jn * 16];
        }
    };

    auto group_fetch = [&](int g) {
#pragma unroll
        for (int jn = 0; jn < 8; ++jn)
            s_raw[jn] = scales[(unsigned)(g * NN) + (unsigned)(colb + jn * 16)];
        unsigned zp = 0;
#pragma unroll
        for (int jn = 0; jn < 8; ++jn) {
            const unsigned u = qzeros[(unsigned)(g * (NN / 8)) + (unsigned)((colb + jn * 16) >> 3)];
            zp |= ((u >> zsh) & 15u) << (4 * jn);
        }
        zp_stage = zp;
    };
    auto group_convert = [&]() {
#pragma unroll
        for (int jn = 0; jn < 8; ++jn) {
            const unsigned short sh = __builtin_bit_cast(unsigned short, (f16)s_raw[jn]);
            s_pk[jn] = ((unsigned)sh << 16) | sh;
            const unsigned nh = 0xE401u + ((zp_stage >> (4 * jn)) & 15u);  // -(1024+z+1)
            nzp[jn] = (nh << 16) | nh;
        }
    };

    // dequant 4 B-fragments in registers + 16 MFMA
    auto phase = [&](int ks, int jh, const f16x8 (&af)[4]) {
        __builtin_amdgcn_s_setprio(1);
#pragma unroll
        for (int j = 0; j < 4; ++j) {
            const int jn = jh * 4 + j;
            const unsigned u = bq[ks * 8 + jn];
            const unsigned t0 = ( u         & 0x000F000Fu) | 0x64006400u;  // (n0,n4)
            const unsigned t1 = ((u >> 4)   & 0x000F000Fu) | 0x64006400u;  // (n1,n5)
            const unsigned t2 = ((u >> 8)   & 0x000F000Fu) | 0x64006400u;  // (n2,n6)
            const unsigned t3 = ((u >> 12)  & 0x000F000Fu) | 0x64006400u;  // (n3,n7)
            const f16x2 z2 = __builtin_bit_cast(f16x2, nzp[jn]);
            const f16x2 sp = __builtin_bit_cast(f16x2, s_pk[jn]);
            const f16x2 w0 = (__builtin_bit_cast(f16x2, t0) + z2) * sp;
            const f16x2 w1 = (__builtin_bit_cast(f16x2, t1) + z2) * sp;
            const f16x2 w2 = (__builtin_bit_cast(f16x2, t2) + z2) * sp;
            const f16x2 w3 = (__builtin_bit_cast(f16x2, t3) + z2) * sp;
            const intx4 bi = { __builtin_bit_cast(int, w0), __builtin_bit_cast(int, w1),
                               __builtin_bit_cast(int, w2), __builtin_bit_cast(int, w3) };
            const f16x8 bfr = __builtin_bit_cast(f16x8, bi);
#pragma unroll
            for (int im = 0; im < 4; ++im)
                acc[im][jn] = __builtin_amdgcn_mfma_f32_16x16x32_f16(
                    af[im], bfr, acc[im][jn], 0, 0, 0);
        }
        __builtin_amdgcn_s_setprio(0);
    };

    // One K-block. `odd` is a compile-time literal at every call site.
    auto body = [&](int kb, int buf, bool stage, bool odd) {
        f16x8 af[4];
        if (!odd && kb > 0) group_convert();   // after barrier: vmcnt already 0
        if (stage) stage_a(kb + 1, buf ^ 1);   // DMA earliest: longest window
        load_af(buf, 0, af);
        phase(0, 0, af);
        if (stage) load_bq(kb + 1, 0, 0);      // reload consumed quarter (WAR)
        phase(0, 1, af);
        if (stage) load_bq(kb + 1, 0, 1);
        if (stage && odd) group_fetch((kb + 1) >> 1);
        load_af(buf, 1, af);
        phase(1, 0, af);
        if (stage) load_bq(kb + 1, 1, 0);
        phase(1, 1, af);
        if (stage) load_bq(kb + 1, 1, 1);
        if (stage) __syncthreads();            // publish As[buf^1]; flip
    };

    // ---- prologue ----
    group_fetch(0);
    group_convert();
    stage_a(0, 0);
    load_bq(0, 0, 0); load_bq(0, 0, 1); load_bq(0, 1, 0); load_bq(0, 1, 1);
    __syncthreads();

    // ---- main loop, unrolled x2 for static buffer indices ----
    for (int kb = 0; kb < NKB - 2; kb += 2) {
        body(kb, 0, true, false);
        body(kb + 1, 1, true, true);
    }
    body(NKB - 2, 0, true, false);
    body(NKB - 1, 1, false, true);

    // ---- epilogue: C/D layout col=lane&15, row=quad*4+reg; add bias ----
#pragma unroll
    for (int jn = 0; jn < 8; ++jn) {
        const int ngl = n0 + wn + jn * 16 + ml;
        const float bv = bias[ngl];
#pragma unroll
        for (int im = 0; im < 4; ++im) {
            const int mg = mtile * BM + wm + im * 16 + quad * 4;
#pragma unroll
            for (int r = 0; r < 4; ++r)
                out[(size_t)(mg + r) * NN + ngl] = acc[im][jn][r] + bv;
        }
    }
}

// ---------------------------------------------------------------------------
// Fallback (round-0 kernel, known-good): used only if ws is too small for xb.
// ---------------------------------------------------------------------------
__global__ __launch_bounds__(THREADS, 2)
void qgemm_fallback(const float* __restrict__ x,
                    const unsigned* __restrict__ qweight,
                    const unsigned* __restrict__ qzeros,
                    const float* __restrict__ scales,
                    const float* __restrict__ bias,
                    float* __restrict__ out)
{
    __shared__ bf16 As[BM * BK];
    __shared__ bf16 Bs[BN * BK];

    const int t = threadIdx.x;
    const int ntile = blockIdx.x & 31;
    const int mtile = blockIdx.x >> 5;
    const int m0 = mtile * BM;
    const int n0 = ntile * BN;
    const int wave = t >> 6;
    const int lane = t & 63;
    const int wm = (wave >> 1) * 64;
    const int wn = (wave & 1) * 128;
    const int ml = lane & 15;
    const int quad = lane >> 4;
    const int bn = t & 255;
    const int rbase = (t >> 8) * 4;
    const int gn = n0 + bn;

    floatx4 acc[4][8];
    for (int i = 0; i < 4; ++i)
        for (int j = 0; j < 8; ++j)
            acc[i][j] = (floatx4){0.f, 0.f, 0.f, 0.f};

    float s = 0.f, sz = 0.f;

    for (int kb = 0; kb < KK / BK; ++kb) {
        const int k0 = kb * BK;
        if ((kb & 1) == 0) {
            const int g = kb >> 1;
            s = scales[g * NN + gn];
            const unsigned zw = qzeros[g * (NN / 8) + (gn >> 3)];
            const float z = (float)(((zw >> (4 * (gn & 7))) & 15u) + 1u);
            sz = s * z;
        }
#pragma unroll
        for (int i = 0; i < 4; ++i) {
            const int chunk = t + THREADS * i;
            const int m = chunk >> 3;
            const int c = chunk & 7;
            const float4* src = (const float4*)(x + (size_t)(m0 + m) * KK + (k0 + c * 8));
            const float4 f0 = src[0];
            const float4 f1 = src[1];
            bf16x8 v;
            v[0] = (bf16)f0.x; v[1] = (bf16)f0.y; v[2] = (bf16)f0.z; v[3] = (bf16)f0.w;
            v[4] = (bf16)f1.x; v[5] = (bf16)f1.y; v[6] = (bf16)f1.z; v[7] = (bf16)f1.w;
            *(bf16x8*)&As[m * BK + ((c ^ (m & 7)) << 3)] = v;
        }
        const int kq0 = k0 >> 3;
#pragma unroll
        for (int i = 0; i < 4; ++i) {
            const int rq = rbase + i;
            const unsigned q = qweight[(size_t)(kq0 + rq) * NN + gn];
            bf16x8 v;
#pragma unroll
            for (int j = 0; j < 8; ++j) {
                const float f = (float)((q >> (4 * j)) & 15u) * s - sz;
                v[j] = (bf16)f;
            }
            *(bf16x8*)&Bs[bn * BK + ((rq ^ (bn & 7)) << 3)] = v;
        }
        __syncthreads();
#pragma unroll
        for (int ks = 0; ks < 2; ++ks) {
            const int clog = ks * 4 + quad;
            bf16x8 af[4];
            bf16x8 bfr[8];
#pragma unroll
            for (int im = 0; im < 4; ++im) {
                const int row = wm + im * 16 + ml;
                af[im] = *(const bf16x8*)&As[row * BK + ((clog ^ (row & 7)) << 3)];
            }
#pragma unroll
            for (int jn = 0; jn < 8; ++jn) {
                const int row = wn + jn * 16 + ml;
                bfr[jn] = *(const bf16x8*)&Bs[row * BK + ((clog ^ (row & 7)) << 3)];
            }
#pragma unroll
            for (int im = 0; im < 4; ++im)
#pragma unroll
                for (int jn = 0; jn < 8; ++jn)
                    acc[im][jn] = __builtin_amdgcn_mfma_f32_16x16x32_bf16(
                        af[im], bfr[jn], acc[im][jn], 0, 0, 0);
        }
        __syncthreads();
    }
#pragma unroll
    for (int jn = 0; jn < 8; ++jn) {
        const int ngl = n0 + wn + jn * 16 + ml;
        const float bv = bias[ngl];
#pragma unroll
        for (int im = 0; im < 4; ++im) {
            const int mg = m0 + wm + im * 16 + quad * 4;
#pragma unroll
            for (int r = 0; r < 4; ++r)
                out[(size_t)(mg + r) * NN + ngl] = acc[im][jn][r] + bv;
        }
    }
}

extern "C" void kernel_launch(void* const* d_in, const int* in_sizes, int n_in,
                              void* d_out, int out_size, void* d_ws, size_t ws_size,
                              hipStream_t stream) {
    const float*    x       = (const float*)d_in[0];
    const unsigned* qweight = (const unsigned*)d_in[1];
    const unsigned* qzeros  = (const unsigned*)d_in[2];
    const float*    scales  = (const float*)d_in[3];
    const float*    bias    = (const float*)d_in[4];
    float* out = (float*)d_out;

    const int grid = (MM / BM) * (NN / BN);   // 512 blocks
    const size_t xb_bytes = (size_t)MM * KK * sizeof(f16);   // 67 MB

    if (ws_size >= xb_bytes) {
        f16* xb = (f16*)d_ws;
        const int chunks = MM * KK / 8;       // 4,194,304
        convert_x<<<chunks / 256, 256, 0, stream>>>(x, xb);
        qgemm<<<grid, THREADS, 0, stream>>>(xb, qweight, qzeros, scales, bias, out);
    } else {
        qgemm_fallback<<<grid, THREADS, 0, stream>>>(x, qweight, qzeros, scales, bias, out);
    }
}

// Round 3
// 795.757 us; speedup vs baseline: 7.2394x; 2.1685x over previous
//
#include <hip/hip_runtime.h>
#include <hip/hip_bf16.h>

// Problem shape (fixed by reference setup_inputs)
constexpr int MM = 4096;   // tokens
constexpr int NN = 8192;   // outfeatures
constexpr int KK = 8192;   // infeatures
constexpr int BM = 256, BN = 256, BK = 64;
constexpr int THREADS = 512;   // 8 waves: 4 along M x 2 along N; wave tile 64x128
constexpr int NKB = KK / BK;   // 128
constexpr int NT = NN / BN;    // 32
constexpr int NG = 64;         // groups

typedef _Float16 f16;
typedef __attribute__((ext_vector_type(2))) _Float16 f16x2;
typedef __attribute__((ext_vector_type(8))) _Float16 f16x8;
typedef __attribute__((ext_vector_type(4))) float floatx4;
typedef __attribute__((ext_vector_type(4))) int intx4;
typedef __bf16 bf16;
typedef __attribute__((ext_vector_type(8))) __bf16 bf16x8;

__device__ __forceinline__ void async_copy16(const void* g, void* l) {
    __builtin_amdgcn_global_load_lds(
        (const __attribute__((address_space(1))) void*)g,
        (__attribute__((address_space(3))) void*)l, 16, 0, 0);
}

// ---------------------------------------------------------------------------
// Prep 1: x fp32 -> f16, tile-major [mtile][kb][m][chunk^swizzle], pair order
// (k0,k4,k1,k5,k2,k6,k3,k7) baked in. 4 chunks/thread for ILP.
// ---------------------------------------------------------------------------
__global__ __launch_bounds__(256)
void convert_x(const float* __restrict__ x, f16* __restrict__ xb) {
    const int base = blockIdx.x * 256 + threadIdx.x;   // 1,048,576 threads
#pragma unroll
    for (int it = 0; it < 4; ++it) {
        const int tid = base + it * 1048576;           // one 16B chunk (8 elems)
        const int c = tid & 7;
        const int m = (tid >> 3) & 255;
        const int kb = (tid >> 11) & 127;
        const int mtile = tid >> 18;
        const int row = mtile * 256 + m;
        const int col = kb * 64 + c * 8;
        const float4* src = (const float4*)(x + (size_t)row * KK + col);
        const float4 f0 = src[0];   // k0..k3
        const float4 f1 = src[1];   // k4..k7
        f16x8 v;                    // pair order (k0,k4,k1,k5,k2,k6,k3,k7)
        v[0] = (f16)f0.x; v[1] = (f16)f1.x;
        v[2] = (f16)f0.y; v[3] = (f16)f1.y;
        v[4] = (f16)f0.z; v[5] = (f16)f1.z;
        v[6] = (f16)f0.w; v[7] = (f16)f1.w;
        const int dst_chunk = (tid & ~7) | (c ^ (m & 7));
        *(f16x8*)(xb + (size_t)dst_chunk * 8) = v;
    }
}

// ---------------------------------------------------------------------------
// Prep 2: permute qweight into per-lane-contiguous consumption order:
//   bpack[ntile][kb][wnh][lane][q][j]  (dwords; q=ks*2+jh, j=0..3)
//   source = qweight[kb*8 + ks*4 + quad][ntile*256 + wnh*128 + ml + (jh*4+j)*16]
// Exact bijection, 33.5 MB. One thread per 16B dest chunk.
// ---------------------------------------------------------------------------
__global__ __launch_bounds__(256)
void prepack_b(const unsigned* __restrict__ qweight, unsigned* __restrict__ bpack) {
    const int C = blockIdx.x * 256 + threadIdx.x;   // 2,097,152 chunks
    const int q    = C & 3;
    const int lane = (C >> 2) & 63;
    const int wnh  = (C >> 8) & 1;
    const int kb   = (C >> 9) & 127;
    const int ntile = C >> 16;
    const int quad = lane >> 4, ml = lane & 15;
    const int ks = q >> 1, jh = q & 1;
    const int row = kb * 8 + ks * 4 + quad;
    const int colbase = ntile * 256 + wnh * 128 + ml + jh * 64;
    intx4 v;
#pragma unroll
    for (int j = 0; j < 4; ++j)
        v[j] = (int)qweight[(size_t)row * NN + colbase + j * 16];
    *(intx4*)(bpack + (size_t)C * 4) = v;
}

// ---------------------------------------------------------------------------
// Prep 3: precompute packed-f16 group constants, per-lane contiguous:
//   spack[ntile][g][wnh][lane][16 dwords] = {s_pk[0..3], s_pk[4..7],
//                                           nzp[0..3],  nzp[4..7]}
//   s_pk = f16(scale) duplicated; nzp = f16 bits of -(1024+z+1) duplicated.
// 16.8 MB (4x duplicated across quads so GEMM loads stay trivial).
// ---------------------------------------------------------------------------
__global__ __launch_bounds__(256)
void prepack_s(const float* __restrict__ scales, const unsigned* __restrict__ qzeros,
               unsigned* __restrict__ spack) {
    const int T = blockIdx.x * 256 + threadIdx.x;   // 262,144 threads
    const int lane = T & 63;
    const int wnh  = (T >> 6) & 1;
    const int g    = (T >> 7) & 63;
    const int ntile = T >> 13;
    const int ml = lane & 15;
    unsigned sp[8], nz[8];
#pragma unroll
    for (int jn = 0; jn < 8; ++jn) {
        const int col = ntile * 256 + wnh * 128 + ml + jn * 16;
        const float s = scales[(size_t)g * NN + col];
        const unsigned zw = qzeros[(size_t)g * (NN / 8) + (col >> 3)];
        const unsigned z = (zw >> (4 * (col & 7))) & 15u;
        const unsigned short sh = __builtin_bit_cast(unsigned short, (f16)s);
        sp[jn] = ((unsigned)sh << 16) | sh;
        const unsigned nh = 0xE401u + z;            // -(1024 + z + 1), exact
        nz[jn] = (nh << 16) | nh;
    }
    unsigned* dst = spack + (size_t)T * 16;
    *(intx4*)(dst + 0)  = (intx4){(int)sp[0], (int)sp[1], (int)sp[2], (int)sp[3]};
    *(intx4*)(dst + 4)  = (intx4){(int)sp[4], (int)sp[5], (int)sp[6], (int)sp[7]};
    *(intx4*)(dst + 8)  = (intx4){(int)nz[0], (int)nz[1], (int)nz[2], (int)nz[3]};
    *(intx4*)(dst + 12) = (intx4){(int)nz[4], (int)nz[5], (int)nz[6], (int)nz[7]};
}

// ---------------------------------------------------------------------------
// Main GEMM.
//  - A: f16 tiles DMA'd via global_load_lds, double-buffered 2x32KB,
//       one barrier per K-block (proven structure).
//  - B: 4x global_load_dwordx4 per K-block per lane from bpack (contiguous),
//       quarter-reloaded right after each phase consumes its quarter.
//       Dequant in registers: t=(u>>s & 0x000F000F)|0x64006400 -> (1024+n_j,
//       1024+n_{j+4}); w=(t + (-(1024+z+1))) * scale  (both steps exact ints
//       before the single mul rounding).
//  - Group constants: 4x dwordx4 from spack, loaded at the END of each odd
//    body (after last use; the barrier's vmcnt(0) drain covers the latency).
// ---------------------------------------------------------------------------
__global__ __launch_bounds__(THREADS, 2)
void qgemm(const f16* __restrict__ xb,
           const unsigned* __restrict__ bpack,
           const unsigned* __restrict__ spack,
           const float* __restrict__ bias,
           float* __restrict__ out)
{
    __shared__ alignas(16) f16 As[2][BM * BK];   // 2 x 32 KB

    const int t = threadIdx.x;
    const int ntile = blockIdx.x & (NT - 1);   // n fastest: share x m-tile
    const int mtile = blockIdx.x / NT;
    const int n0 = ntile * BN;

    const int wave = t >> 6;
    const int lane = t & 63;
    const int wm = (wave >> 1) * 64;    // 4 waves along M
    const int wn = (wave & 1) * 128;    // 2 waves along N
    const int ml = lane & 15;
    const int quad = lane >> 4;
    const int wnh = wave & 1;

    floatx4 acc[4][8];
#pragma unroll
    for (int i = 0; i < 4; ++i)
#pragma unroll
        for (int j = 0; j < 8; ++j)
            acc[i][j] = (floatx4){0.f, 0.f, 0.f, 0.f};

    // ---- state registers ----
    unsigned bq[16];            // raw qweight dwords for current kb
    unsigned s_pk[8], nzp[8];   // current group constants

    const char* xb_base = (const char*)xb
        + (size_t)mtile * NKB * (BM * BK) * sizeof(f16);
    // per-lane bases into the prepacked streams (dword indices)
    const unsigned bq_base0 = ((unsigned)(ntile * 128) * 2 + wnh) * 1024u + lane * 16u;
    const unsigned sp_base0 = ((unsigned)(ntile * 64) * 2 + wnh) * 1024u + lane * 16u;

    auto stage_a = [&](int kb, int buf) {
        const char* g = xb_base + (size_t)kb * (BM * BK * 2) + wave * 4096 + lane * 16;
        char* l = (char*)&As[buf][0] + wave * 4096;   // wave-uniform; HW adds lane*16
#pragma unroll
        for (int i = 0; i < 4; ++i)
            async_copy16(g + i * 1024, l + i * 1024);
    };

    auto load_af = [&](int buf, int ks, f16x8 (&af)[4]) {
#pragma unroll
        for (int im = 0; im < 4; ++im) {
            const int r = wm + im * 16 + ml;
            const int clog = ks * 4 + quad;
            af[im] = *(const f16x8*)&As[buf][r * BK + ((clog ^ (r & 7)) << 3)];
        }
    };

    auto load_bq = [&](int kb, int q) {
        const unsigned idx = bq_base0 + (unsigned)kb * 2048u + (unsigned)q * 4u;
        *(intx4*)&bq[q * 4] = *(const intx4*)(bpack + idx);
    };

    auto load_grp = [&](int g) {
        const unsigned idx = sp_base0 + (unsigned)g * 2048u;
        *(intx4*)&s_pk[0] = *(const intx4*)(spack + idx);
        *(intx4*)&s_pk[4] = *(const intx4*)(spack + idx + 4);
        *(intx4*)&nzp[0]  = *(const intx4*)(spack + idx + 8);
        *(intx4*)&nzp[4]  = *(const intx4*)(spack + idx + 12);
    };

    // dequant 4 B-fragments in registers + 16 MFMA
    auto phase = [&](int ks, int jh, const f16x8 (&af)[4]) {
        __builtin_amdgcn_s_setprio(1);
#pragma unroll
        for (int j = 0; j < 4; ++j) {
            const int jn = jh * 4 + j;
            const unsigned u = bq[(ks * 2 + jh) * 4 + j];
            const unsigned t0 = ( u         & 0x000F000Fu) | 0x64006400u;  // (n0,n4)
            const unsigned t1 = ((u >> 4)   & 0x000F000Fu) | 0x64006400u;  // (n1,n5)
            const unsigned t2 = ((u >> 8)   & 0x000F000Fu) | 0x64006400u;  // (n2,n6)
            const unsigned t3 = ((u >> 12)  & 0x000F000Fu) | 0x64006400u;  // (n3,n7)
            const f16x2 z2 = __builtin_bit_cast(f16x2, nzp[jn]);
            const f16x2 sp = __builtin_bit_cast(f16x2, s_pk[jn]);
            const f16x2 w0 = (__builtin_bit_cast(f16x2, t0) + z2) * sp;
            const f16x2 w1 = (__builtin_bit_cast(f16x2, t1) + z2) * sp;
            const f16x2 w2 = (__builtin_bit_cast(f16x2, t2) + z2) * sp;
            const f16x2 w3 = (__builtin_bit_cast(f16x2, t3) + z2) * sp;
            const intx4 bi = { __builtin_bit_cast(int, w0), __builtin_bit_cast(int, w1),
                               __builtin_bit_cast(int, w2), __builtin_bit_cast(int, w3) };
            const f16x8 bfr = __builtin_bit_cast(f16x8, bi);
#pragma unroll
            for (int im = 0; im < 4; ++im)
                acc[im][jn] = __builtin_amdgcn_mfma_f32_16x16x32_f16(
                    af[im], bfr, acc[im][jn], 0, 0, 0);
        }
        __builtin_amdgcn_s_setprio(0);
    };

    // One K-block. `odd` is a compile-time literal at every call site.
    auto body = [&](int kb, int buf, bool stage, bool odd) {
        f16x8 af[4];
        if (stage) stage_a(kb + 1, buf ^ 1);   // DMA earliest: longest window
        load_af(buf, 0, af);
        phase(0, 0, af);
        if (stage) load_bq(kb + 1, 0);         // reload consumed quarter (WAR)
        phase(0, 1, af);
        if (stage) load_bq(kb + 1, 1);
        load_af(buf, 1, af);
        phase(1, 0, af);
        if (stage) load_bq(kb + 1, 2);
        phase(1, 1, af);
        if (stage) load_bq(kb + 1, 3);
        if (stage && odd) load_grp((kb + 1) >> 1);  // after last use of group
        if (stage) __syncthreads();            // drains DMA + bq + grp loads
    };

    // ---- prologue ----
    load_grp(0);
    stage_a(0, 0);
    load_bq(0, 0); load_bq(0, 1); load_bq(0, 2); load_bq(0, 3);
    __syncthreads();

    // ---- main loop, unrolled x2 for static buffer indices ----
    for (int kb = 0; kb < NKB - 2; kb += 2) {
        body(kb, 0, true, false);
        body(kb + 1, 1, true, true);
    }
    body(NKB - 2, 0, true, false);
    body(NKB - 1, 1, false, true);

    // ---- epilogue: C/D layout col=lane&15, row=quad*4+reg; add bias ----
#pragma unroll
    for (int jn = 0; jn < 8; ++jn) {
        const int ngl = n0 + wn + jn * 16 + ml;
        const float bv = bias[ngl];
#pragma unroll
        for (int im = 0; im < 4; ++im) {
            const int mg = mtile * BM + wm + im * 16 + quad * 4;
#pragma unroll
            for (int r = 0; r < 4; ++r)
                out[(size_t)(mg + r) * NN + ngl] = acc[im][jn][r] + bv;
        }
    }
}

// ---------------------------------------------------------------------------
// Fallback (round-0 structure, known-good): used only if ws is too small.
// ---------------------------------------------------------------------------
__global__ __launch_bounds__(THREADS, 2)
void qgemm_fallback(const float* __restrict__ x,
                    const unsigned* __restrict__ qweight,
                    const unsigned* __restrict__ qzeros,
                    const float* __restrict__ scales,
                    const float* __restrict__ bias,
                    float* __restrict__ out)
{
    __shared__ bf16 As[BM * BK];
    __shared__ bf16 Bs[BN * BK];

    const int t = threadIdx.x;
    const int ntile = blockIdx.x & 31;
    const int mtile = blockIdx.x >> 5;
    const int m0 = mtile * BM;
    const int n0 = ntile * BN;
    const int wave = t >> 6;
    const int lane = t & 63;
    const int wm = (wave >> 1) * 64;
    const int wn = (wave & 1) * 128;
    const int ml = lane & 15;
    const int quad = lane >> 4;
    const int bn = t & 255;
    const int rbase = (t >> 8) * 4;
    const int gn = n0 + bn;

    floatx4 acc[4][8];
    for (int i = 0; i < 4; ++i)
        for (int j = 0; j < 8; ++j)
            acc[i][j] = (floatx4){0.f, 0.f, 0.f, 0.f};

    float s = 0.f, sz = 0.f;

    for (int kb = 0; kb < KK / BK; ++kb) {
        const int k0 = kb * BK;
        if ((kb & 1) == 0) {
            const int g = kb >> 1;
            s = scales[g * NN + gn];
            const unsigned zw = qzeros[g * (NN / 8) + (gn >> 3)];
            const float z = (float)(((zw >> (4 * (gn & 7))) & 15u) + 1u);
            sz = s * z;
        }
#pragma unroll
        for (int i = 0; i < 4; ++i) {
            const int chunk = t + THREADS * i;
            const int m = chunk >> 3;
            const int c = chunk & 7;
            const float4* src = (const float4*)(x + (size_t)(m0 + m) * KK + (k0 + c * 8));
            const float4 f0 = src[0];
            const float4 f1 = src[1];
            bf16x8 v;
            v[0] = (bf16)f0.x; v[1] = (bf16)f0.y; v[2] = (bf16)f0.z; v[3] = (bf16)f0.w;
            v[4] = (bf16)f1.x; v[5] = (bf16)f1.y; v[6] = (bf16)f1.z; v[7] = (bf16)f1.w;
            *(bf16x8*)&As[m * BK + ((c ^ (m & 7)) << 3)] = v;
        }
        const int kq0 = k0 >> 3;
#pragma unroll
        for (int i = 0; i < 4; ++i) {
            const int rq = rbase + i;
            const unsigned q = qweight[(size_t)(kq0 + rq) * NN + gn];
            bf16x8 v;
#pragma unroll
            for (int j = 0; j < 8; ++j) {
                const float f = (float)((q >> (4 * j)) & 15u) * s - sz;
                v[j] = (bf16)f;
            }
            *(bf16x8*)&Bs[bn * BK + ((rq ^ (bn & 7)) << 3)] = v;
        }
        __syncthreads();
#pragma unroll
        for (int ks = 0; ks < 2; ++ks) {
            const int clog = ks * 4 + quad;
            bf16x8 af[4];
            bf16x8 bfr[8];
#pragma unroll
            for (int im = 0; im < 4; ++im) {
                const int row = wm + im * 16 + ml;
                af[im] = *(const bf16x8*)&As[row * BK + ((clog ^ (row & 7)) << 3)];
            }
#pragma unroll
            for (int jn = 0; jn < 8; ++jn) {
                const int row = wn + jn * 16 + ml;
                bfr[jn] = *(const bf16x8*)&Bs[row * BK + ((clog ^ (row & 7)) << 3)];
            }
#pragma unroll
            for (int im = 0; im < 4; ++im)
#pragma unroll
                for (int jn = 0; jn < 8; ++jn)
                    acc[im][jn] = __builtin_amdgcn_mfma_f32_16x16x32_bf16(
                        af[im], bfr[jn], acc[im][jn], 0, 0, 0);
        }
        __syncthreads();
    }
#pragma unroll
    for (int jn = 0; jn < 8; ++jn) {
        const int ngl = n0 + wn + jn * 16 + ml;
        const float bv = bias[ngl];
#pragma unroll
        for (int im = 0; im < 4; ++im) {
            const int mg = m0 + wm + im * 16 + quad * 4;
#pragma unroll
            for (int r = 0; r < 4; ++r)
                out[(size_t)(mg + r) * NN + ngl] = acc[im][jn][r] + bv;
        }
    }
}

extern "C" void kernel_launch(void* const* d_in, const int* in_sizes, int n_in,
                              void* d_out, int out_size, void* d_ws, size_t ws_size,
                              hipStream_t stream) {
    const float*    x       = (const float*)d_in[0];
    const unsigned* qweight = (const unsigned*)d_in[1];
    const unsigned* qzeros  = (const unsigned*)d_in[2];
    const float*    scales  = (const float*)d_in[3];
    const float*    bias    = (const float*)d_in[4];
    float* out = (float*)d_out;

    const int grid = (MM / BM) * (NN / BN);   // 512 blocks

    const size_t xb_bytes = (size_t)MM * KK * sizeof(f16);        // 64 MiB
    const size_t bp_bytes = (size_t)(KK / 8) * NN * 4;            // 32 MiB
    const size_t sp_bytes = (size_t)32 * 64 * 2 * 64 * 16 * 4;    // 16 MiB

    if (ws_size >= xb_bytes + bp_bytes + sp_bytes) {
        f16*      xb    = (f16*)d_ws;
        unsigned* bpack = (unsigned*)((char*)d_ws + xb_bytes);
        unsigned* spack = (unsigned*)((char*)d_ws + xb_bytes + bp_bytes);
        convert_x<<<4096, 256, 0, stream>>>(x, xb);
        prepack_b<<<8192, 256, 0, stream>>>(qweight, bpack);
        prepack_s<<<1024, 256, 0, stream>>>(scales, qzeros, spack);
        qgemm<<<grid, THREADS, 0, stream>>>(xb, bpack, spack, bias, out);
    } else {
        qgemm_fallback<<<grid, THREADS, 0, stream>>>(x, qweight, qzeros, scales, bias, out);
    }
}

// Round 4
// 778.929 us; speedup vs baseline: 7.3958x; 1.0216x over previous
//
#include <hip/hip_runtime.h>
#include <hip/hip_bf16.h>

// Problem shape (fixed by reference setup_inputs)
constexpr int MM = 4096;   // tokens
constexpr int NN = 8192;   // outfeatures
constexpr int KK = 8192;   // infeatures
// Main kernel tile: 128x256, 8 waves (2M x 4N), wave tile 64x64
constexpr int AM = 128, AN = 256, BK = 64;
constexpr int THREADS = 512;
constexpr int NKB = KK / BK;    // 128
constexpr int NTN = NN / AN;    // 32 n-tiles
constexpr int NTM = MM / AM;    // 32 m-tiles

typedef _Float16 f16;
typedef __attribute__((ext_vector_type(2))) _Float16 f16x2;
typedef __attribute__((ext_vector_type(8))) _Float16 f16x8;
typedef __attribute__((ext_vector_type(4))) float floatx4;
typedef __attribute__((ext_vector_type(4))) int intx4;
typedef __bf16 bf16;
typedef __attribute__((ext_vector_type(8))) __bf16 bf16x8;

__device__ __forceinline__ void async_copy16(const void* g, void* l) {
    __builtin_amdgcn_global_load_lds(
        (const __attribute__((address_space(1))) void*)g,
        (__attribute__((address_space(3))) void*)l, 16, 0, 0);
}

// ---------------------------------------------------------------------------
// Prep 1: x fp32 -> f16, tile-major [mtile(32)][kb(128)][m(128)][chunk^swz],
// pair order (k0,k4,k1,k5,k2,k6,k3,k7) baked in. 4 chunks/thread.
// ---------------------------------------------------------------------------
__global__ __launch_bounds__(256)
void convert_x(const float* __restrict__ x, f16* __restrict__ xb) {
    const int base = blockIdx.x * 256 + threadIdx.x;   // 1,048,576 threads
#pragma unroll
    for (int it = 0; it < 4; ++it) {
        const int tid = base + it * 1048576;           // one 16B chunk (8 elems)
        const int c = tid & 7;
        const int m = (tid >> 3) & 127;
        const int kb = (tid >> 10) & 127;
        const int mtile = tid >> 17;
        const int row = mtile * AM + m;
        const int col = kb * 64 + c * 8;
        const float4* src = (const float4*)(x + (size_t)row * KK + col);
        const float4 f0 = src[0];   // k0..k3
        const float4 f1 = src[1];   // k4..k7
        f16x8 v;                    // pair order (k0,k4,k1,k5,k2,k6,k3,k7)
        v[0] = (f16)f0.x; v[1] = (f16)f1.x;
        v[2] = (f16)f0.y; v[3] = (f16)f1.y;
        v[4] = (f16)f0.z; v[5] = (f16)f1.z;
        v[6] = (f16)f0.w; v[7] = (f16)f1.w;
        const int dst_chunk = (tid & ~7) | (c ^ (m & 7));
        *(f16x8*)(xb + (size_t)dst_chunk * 8) = v;
    }
}

// ---------------------------------------------------------------------------
// Prep 2: permute qweight into per-lane consumption order:
//   bpack[ntile(32)][kb(128)][wq(4)][lane(64)][ks(2)][j(4)]  (dwords)
//   source = qweight[kb*8 + ks*4 + quad][ntile*256 + wq*64 + ml + j*16]
// Exact bijection, 32 MiB. One thread per 16B dest chunk (one ks half).
// ---------------------------------------------------------------------------
__global__ __launch_bounds__(256)
void prepack_b(const unsigned* __restrict__ qweight, unsigned* __restrict__ bpack) {
    const int C = blockIdx.x * 256 + threadIdx.x;   // 2,097,152 chunks
    const int ks   = C & 1;
    const int lane = (C >> 1) & 63;
    const int wq   = (C >> 7) & 3;
    const int kb   = (C >> 9) & 127;
    const int ntile = C >> 16;
    const int quad = lane >> 4, ml = lane & 15;
    const int row = kb * 8 + ks * 4 + quad;
    const int colbase = ntile * 256 + wq * 64 + ml;
    intx4 v;
#pragma unroll
    for (int j = 0; j < 4; ++j)
        v[j] = (int)qweight[(size_t)row * NN + colbase + j * 16];
    *(intx4*)(bpack + (size_t)C * 4) = v;
}

// ---------------------------------------------------------------------------
// Prep 3: packed-f16 group constants, per-lane contiguous:
//   spack[ntile(32)][g(64)][wq(4)][lane(64)][8 dwords] = {s_pk[0..3], nzp[0..3]}
//   s_pk = f16(scale) duplicated; nzp = f16 bits of -(1024+z+1) duplicated.
// 16 MiB (duplicated across quads so GEMM loads are trivial dwordx4).
// ---------------------------------------------------------------------------
__global__ __launch_bounds__(256)
void prepack_s(const float* __restrict__ scales, const unsigned* __restrict__ qzeros,
               unsigned* __restrict__ spack) {
    const int T = blockIdx.x * 256 + threadIdx.x;   // 524,288 threads
    const int lane = T & 63;
    const int wq   = (T >> 6) & 3;
    const int g    = (T >> 8) & 63;
    const int ntile = T >> 14;
    const int ml = lane & 15;
    unsigned sp[4], nz[4];
#pragma unroll
    for (int jn = 0; jn < 4; ++jn) {
        const int col = ntile * 256 + wq * 64 + ml + jn * 16;
        const float s = scales[(size_t)g * NN + col];
        const unsigned zw = qzeros[(size_t)g * (NN / 8) + (col >> 3)];
        const unsigned z = (zw >> (4 * (col & 7))) & 15u;
        const unsigned short sh = __builtin_bit_cast(unsigned short, (f16)s);
        sp[jn] = ((unsigned)sh << 16) | sh;
        const unsigned nh = 0xE401u + z;            // -(1024 + z + 1), exact
        nz[jn] = (nh << 16) | nh;
    }
    unsigned* dst = spack + (size_t)T * 8;
    *(intx4*)(dst + 0) = (intx4){(int)sp[0], (int)sp[1], (int)sp[2], (int)sp[3]};
    *(intx4*)(dst + 4) = (intx4){(int)nz[0], (int)nz[1], (int)nz[2], (int)nz[3]};
}

// ---------------------------------------------------------------------------
// Main GEMM. 128x256 tile, 8 waves (2M x 4N), wave tile 64x64, acc = 64 AGPR,
// launch_bounds(512,4) => <=128 regs/wave => 2 blocks/CU (16 waves).
//  - A: f16 tiles via global_load_lds, double-buffered 2x16KB, 1 barrier/kb.
//  - B: 2x dwordx4/lane/kb from bpack, dequant in regs (packed-f16 magic,
//    exact add-then-mul). Dup factor across M-waves: 2 (was 4).
//  - Group constants: 2x dwordx4 from spack at end of odd kb.
//  - Bijective XCD-chunk swizzle: co-resident blocks on an XCD share ~2
//    A-mtiles (4 MB ~= L2) instead of 16 via L3.
// ---------------------------------------------------------------------------
__global__ __launch_bounds__(THREADS, 4)
void qgemm(const f16* __restrict__ xb,
           const unsigned* __restrict__ bpack,
           const unsigned* __restrict__ spack,
           const float* __restrict__ bias,
           float* __restrict__ out)
{
    __shared__ alignas(16) f16 As[2][AM * BK];   // 2 x 16 KB

    const int t = threadIdx.x;
    // XCD-chunk swizzle (1024 % 8 == 0 -> bijective)
    const int v = (blockIdx.x & 7) * 128 + (blockIdx.x >> 3);
    const int ntile = v & (NTN - 1);
    const int mtile = v >> 5;
    const int n0 = ntile * AN;

    const int wave = t >> 6;
    const int lane = t & 63;
    const int wm = (wave >> 2) * 64;    // 2 waves along M
    const int wn = (wave & 3) * 64;     // 4 waves along N
    const int ml = lane & 15;
    const int quad = lane >> 4;
    const int wq = wave & 3;

    floatx4 acc[4][4];
#pragma unroll
    for (int i = 0; i < 4; ++i)
#pragma unroll
        for (int j = 0; j < 4; ++j)
            acc[i][j] = (floatx4){0.f, 0.f, 0.f, 0.f};

    // ---- state registers ----
    unsigned bq[8];             // raw qweight dwords for current kb [ks*4+j]
    unsigned s_pk[4], nzp[4];   // current group constants

    const char* xb_base = (const char*)xb
        + (size_t)mtile * NKB * (AM * BK) * sizeof(f16);
    // per-lane bases (dword indices)
    const unsigned bq_base0 = (unsigned)ntile * 262144u + (unsigned)wq * 512u + lane * 8u;
    const unsigned sp_base0 = (unsigned)ntile * 131072u + (unsigned)wq * 512u + lane * 8u;

    auto stage_a = [&](int kb, int buf) {
        const char* g = xb_base + (size_t)kb * (AM * BK * 2)
                      + wave * 2048 + lane * 16;
        char* l = (char*)&As[buf][0] + wave * 2048;   // wave-uniform; HW adds lane*16
#pragma unroll
        for (int i = 0; i < 2; ++i)
            async_copy16(g + i * 1024, l + i * 1024);
    };

    auto load_af = [&](int buf, int ks, f16x8 (&af)[4]) {
#pragma unroll
        for (int im = 0; im < 4; ++im) {
            const int r = wm + im * 16 + ml;
            const int clog = ks * 4 + quad;
            af[im] = *(const f16x8*)&As[buf][r * BK + ((clog ^ (r & 7)) << 3)];
        }
    };

    auto load_bq = [&](int kb, int ks) {
        const unsigned idx = bq_base0 + (unsigned)kb * 2048u + (unsigned)ks * 4u;
        *(intx4*)&bq[ks * 4] = *(const intx4*)(bpack + idx);
    };

    auto load_grp = [&](int g) {
        const unsigned idx = sp_base0 + (unsigned)g * 2048u;
        *(intx4*)&s_pk[0] = *(const intx4*)(spack + idx);
        *(intx4*)&nzp[0]  = *(const intx4*)(spack + idx + 4);
    };

    // dequant 4 B-fragments in registers + 16 MFMA
    auto phase = [&](int ks, const f16x8 (&af)[4]) {
        __builtin_amdgcn_s_setprio(1);
#pragma unroll
        for (int j = 0; j < 4; ++j) {
            const unsigned u = bq[ks * 4 + j];
            const unsigned t0 = ( u         & 0x000F000Fu) | 0x64006400u;  // (n0,n4)
            const unsigned t1 = ((u >> 4)   & 0x000F000Fu) | 0x64006400u;  // (n1,n5)
            const unsigned t2 = ((u >> 8)   & 0x000F000Fu) | 0x64006400u;  // (n2,n6)
            const unsigned t3 = ((u >> 12)  & 0x000F000Fu) | 0x64006400u;  // (n3,n7)
            const f16x2 z2 = __builtin_bit_cast(f16x2, nzp[j]);
            const f16x2 sp = __builtin_bit_cast(f16x2, s_pk[j]);
            const f16x2 w0 = (__builtin_bit_cast(f16x2, t0) + z2) * sp;
            const f16x2 w1 = (__builtin_bit_cast(f16x2, t1) + z2) * sp;
            const f16x2 w2 = (__builtin_bit_cast(f16x2, t2) + z2) * sp;
            const f16x2 w3 = (__builtin_bit_cast(f16x2, t3) + z2) * sp;
            const intx4 bi = { __builtin_bit_cast(int, w0), __builtin_bit_cast(int, w1),
                               __builtin_bit_cast(int, w2), __builtin_bit_cast(int, w3) };
            const f16x8 bfr = __builtin_bit_cast(f16x8, bi);
#pragma unroll
            for (int im = 0; im < 4; ++im)
                acc[im][j] = __builtin_amdgcn_mfma_f32_16x16x32_f16(
                    af[im], bfr, acc[im][j], 0, 0, 0);
        }
        __builtin_amdgcn_s_setprio(0);
    };

    // One K-block. `odd` is a compile-time literal at every call site.
    auto body = [&](int kb, int buf, bool stage, bool odd) {
        f16x8 af[4];
        if (stage) stage_a(kb + 1, buf ^ 1);   // DMA earliest: longest window
        load_af(buf, 0, af);
        phase(0, af);
        if (stage) load_bq(kb + 1, 0);         // reload consumed half (WAR)
        load_af(buf, 1, af);
        phase(1, af);
        if (stage) load_bq(kb + 1, 1);
        if (stage && odd) load_grp((kb + 1) >> 1);  // after last use of group
        if (stage) __syncthreads();            // drains DMA + bq + grp loads
    };

    // ---- prologue ----
    load_grp(0);
    stage_a(0, 0);
    load_bq(0, 0); load_bq(0, 1);
    __syncthreads();

    // ---- main loop, unrolled x2 for static buffer indices ----
    for (int kb = 0; kb < NKB - 2; kb += 2) {
        body(kb, 0, true, false);
        body(kb + 1, 1, true, true);
    }
    body(NKB - 2, 0, true, false);
    body(NKB - 1, 1, false, true);

    // ---- epilogue: C/D layout col=lane&15, row=quad*4+reg; add bias ----
#pragma unroll
    for (int jn = 0; jn < 4; ++jn) {
        const int ngl = n0 + wn + jn * 16 + ml;
        const float bv = bias[ngl];
#pragma unroll
        for (int im = 0; im < 4; ++im) {
            const int mg = mtile * AM + wm + im * 16 + quad * 4;
#pragma unroll
            for (int r = 0; r < 4; ++r)
                out[(size_t)(mg + r) * NN + ngl] = acc[im][jn][r] + bv;
        }
    }
}

// ---------------------------------------------------------------------------
// Fallback (round-0 structure, known-good, 256x256): only if ws too small.
// ---------------------------------------------------------------------------
__global__ __launch_bounds__(512, 2)
void qgemm_fallback(const float* __restrict__ x,
                    const unsigned* __restrict__ qweight,
                    const unsigned* __restrict__ qzeros,
                    const float* __restrict__ scales,
                    const float* __restrict__ bias,
                    float* __restrict__ out)
{
    constexpr int FBM = 256, FBN = 256;
    __shared__ bf16 As[FBM * BK];
    __shared__ bf16 Bs[FBN * BK];

    const int t = threadIdx.x;
    const int ntile = blockIdx.x & 31;
    const int mtile = blockIdx.x >> 5;
    const int m0 = mtile * FBM;
    const int n0 = ntile * FBN;
    const int wave = t >> 6;
    const int lane = t & 63;
    const int wm = (wave >> 1) * 64;
    const int wn = (wave & 1) * 128;
    const int ml = lane & 15;
    const int quad = lane >> 4;
    const int bn = t & 255;
    const int rbase = (t >> 8) * 4;
    const int gn = n0 + bn;

    floatx4 acc[4][8];
    for (int i = 0; i < 4; ++i)
        for (int j = 0; j < 8; ++j)
            acc[i][j] = (floatx4){0.f, 0.f, 0.f, 0.f};

    float s = 0.f, sz = 0.f;

    for (int kb = 0; kb < KK / BK; ++kb) {
        const int k0 = kb * BK;
        if ((kb & 1) == 0) {
            const int g = kb >> 1;
            s = scales[g * NN + gn];
            const unsigned zw = qzeros[g * (NN / 8) + (gn >> 3)];
            const float z = (float)(((zw >> (4 * (gn & 7))) & 15u) + 1u);
            sz = s * z;
        }
#pragma unroll
        for (int i = 0; i < 4; ++i) {
            const int chunk = t + 512 * i;
            const int m = chunk >> 3;
            const int c = chunk & 7;
            const float4* src = (const float4*)(x + (size_t)(m0 + m) * KK + (k0 + c * 8));
            const float4 f0 = src[0];
            const float4 f1 = src[1];
            bf16x8 v;
            v[0] = (bf16)f0.x; v[1] = (bf16)f0.y; v[2] = (bf16)f0.z; v[3] = (bf16)f0.w;
            v[4] = (bf16)f1.x; v[5] = (bf16)f1.y; v[6] = (bf16)f1.z; v[7] = (bf16)f1.w;
            *(bf16x8*)&As[m * BK + ((c ^ (m & 7)) << 3)] = v;
        }
        const int kq0 = k0 >> 3;
#pragma unroll
        for (int i = 0; i < 4; ++i) {
            const int rq = rbase + i;
            const unsigned q = qweight[(size_t)(kq0 + rq) * NN + gn];
            bf16x8 v;
#pragma unroll
            for (int j = 0; j < 8; ++j) {
                const float f = (float)((q >> (4 * j)) & 15u) * s - sz;
                v[j] = (bf16)f;
            }
            *(bf16x8*)&Bs[bn * BK + ((rq ^ (bn & 7)) << 3)] = v;
        }
        __syncthreads();
#pragma unroll
        for (int ks = 0; ks < 2; ++ks) {
            const int clog = ks * 4 + quad;
            bf16x8 af[4];
            bf16x8 bfr[8];
#pragma unroll
            for (int im = 0; im < 4; ++im) {
                const int row = wm + im * 16 + ml;
                af[im] = *(const bf16x8*)&As[row * BK + ((clog ^ (row & 7)) << 3)];
            }
#pragma unroll
            for (int jn = 0; jn < 8; ++jn) {
                const int row = wn + jn * 16 + ml;
                bfr[jn] = *(const bf16x8*)&Bs[row * BK + ((clog ^ (row & 7)) << 3)];
            }
#pragma unroll
            for (int im = 0; im < 4; ++im)
#pragma unroll
                for (int jn = 0; jn < 8; ++jn)
                    acc[im][jn] = __builtin_amdgcn_mfma_f32_16x16x32_bf16(
                        af[im], bfr[jn], acc[im][jn], 0, 0, 0);
        }
        __syncthreads();
    }
#pragma unroll
    for (int jn = 0; jn < 8; ++jn) {
        const int ngl = n0 + wn + jn * 16 + ml;
        const float bv = bias[ngl];
#pragma unroll
        for (int im = 0; im < 4; ++im) {
            const int mg = m0 + wm + im * 16 + quad * 4;
#pragma unroll
            for (int r = 0; r < 4; ++r)
                out[(size_t)(mg + r) * NN + ngl] = acc[im][jn][r] + bv;
        }
    }
}

extern "C" void kernel_launch(void* const* d_in, const int* in_sizes, int n_in,
                              void* d_out, int out_size, void* d_ws, size_t ws_size,
                              hipStream_t stream) {
    const float*    x       = (const float*)d_in[0];
    const unsigned* qweight = (const unsigned*)d_in[1];
    const unsigned* qzeros  = (const unsigned*)d_in[2];
    const float*    scales  = (const float*)d_in[3];
    const float*    bias    = (const float*)d_in[4];
    float* out = (float*)d_out;

    const size_t xb_bytes = (size_t)MM * KK * sizeof(f16);        // 64 MiB
    const size_t bp_bytes = (size_t)(KK / 8) * NN * 4;            // 32 MiB
    const size_t sp_bytes = (size_t)32 * 64 * 4 * 64 * 8 * 4;     // 16 MiB

    if (ws_size >= xb_bytes + bp_bytes + sp_bytes) {
        f16*      xb    = (f16*)d_ws;
        unsigned* bpack = (unsigned*)((char*)d_ws + xb_bytes);
        unsigned* spack = (unsigned*)((char*)d_ws + xb_bytes + bp_bytes);
        convert_x<<<4096, 256, 0, stream>>>(x, xb);
        prepack_b<<<8192, 256, 0, stream>>>(qweight, bpack);
        prepack_s<<<2048, 256, 0, stream>>>(scales, qzeros, spack);
        const int grid = NTM * NTN;   // 1024 blocks
        qgemm<<<grid, THREADS, 0, stream>>>(xb, bpack, spack, bias, out);
    } else {
        const int grid = (MM / 256) * (NN / 256);   // 512 blocks
        qgemm_fallback<<<grid, 512, 0, stream>>>(x, qweight, qzeros, scales, bias, out);
    }
}